// Round 1
// baseline (813.928 us; speedup 1.0000x reference)
//
#include <hip/hip_runtime.h>

#define TOKENS 8192
#define INF 512
#define HIDDEN 1024
#define NEXP 16

typedef short bh4 __attribute__((ext_vector_type(4)));
typedef short bh8 __attribute__((ext_vector_type(8)));
typedef float f32x4 __attribute__((ext_vector_type(4)));

__device__ __forceinline__ short f2b(float f) {
  union { float f; unsigned u; } v; v.f = f;
  unsigned r = v.u + 0x7FFFu + ((v.u >> 16) & 1u);
  return (short)(r >> 16);
}
__device__ __forceinline__ float b2f(short h) {
  union { unsigned u; float f; } v; v.u = ((unsigned)(unsigned short)h) << 16;
  return v.f;
}
__device__ __forceinline__ float silu_f(float x) { return x / (1.f + __expf(-x)); }

// MFMA via inline asm: sidesteps builtin operand-type (short8 vs __bf16x8) ambiguity.
// ISA operand order: D, A, B, C ; D tied to C via "+v".
__device__ __forceinline__ f32x4 mfma_16x16x32_bf16(bh8 a, bh8 b, f32x4 c) {
  asm("v_mfma_f32_16x16x32_bf16 %0, %1, %2, %0" : "+v"(c) : "v"(a), "v"(b));
  return c;
}

// ---------------- fp32 -> bf16 convert (vectorized) ----------------
__global__ __launch_bounds__(256) void convert_kernel(const float* __restrict__ in,
                                                      short* __restrict__ out, int n) {
  int nv = n >> 2;
  int stride = gridDim.x * blockDim.x;
  for (int i = blockIdx.x * blockDim.x + threadIdx.x; i < nv; i += stride) {
    float4 v = ((const float4*)in)[i];
    bh4 o;
    o[0] = f2b(v.x); o[1] = f2b(v.y); o[2] = f2b(v.z); o[3] = f2b(v.w);
    *(bh4*)(out + (size_t)i * 4) = o;
  }
}

// ---------------- batched transpose fp32 [R][C] -> bf16 [C][R] ----------------
__global__ __launch_bounds__(256) void transpose_kernel(const float* __restrict__ in,
                                                        short* __restrict__ out,
                                                        int R, int C) {
  __shared__ float tile[32][33];
  size_t base = (size_t)blockIdx.z * (size_t)R * (size_t)C;
  int c0 = blockIdx.x * 32, r0 = blockIdx.y * 32;
  int tx = threadIdx.x, ty = threadIdx.y;  // block (32,8)
  #pragma unroll
  for (int i = 0; i < 32; i += 8)
    tile[ty + i][tx] = in[base + (size_t)(r0 + ty + i) * C + (c0 + tx)];
  __syncthreads();
  #pragma unroll
  for (int i = 0; i < 32; i += 8)
    out[base + (size_t)(c0 + ty + i) * R + (r0 + tx)] = f2b(tile[tx][ty + i]);
}

// ---------------- 128x128-tile bf16 MFMA GEMM ----------------
// A: [M][K] bf16 row-major. Bt: [N][K] bf16 row-major (pre-transposed weights).
// MODE 0: C[m][n] = bf16(silu(acc + bias[n]))
// MODE 1: expert_out[m*NEXP+eidx] += sum_n silu(acc + bias[n]) * w3[n]   (no C write)
// LDS layout: [row][col] with col XOR-swizzled by (row&7)<<3 (elem units) to kill
// the 16-way bank conflict of stride-128B rows; global_load_lds dest is linear so
// the *source* column is pre-swizzled with the same involution (rule #21).
template <int MODE>
__global__ __launch_bounds__(256) void gemm_bf16(
    const short* __restrict__ A, const short* __restrict__ Bt,
    const float* __restrict__ bias, short* __restrict__ C,
    const float* __restrict__ w3, float* __restrict__ eout, int eidx,
    int M, int N, int K) {
  __shared__ short As[128][64];
  __shared__ short Bs[128][64];
  const int tid = threadIdx.x;
  const int lane = tid & 63;
  const int wid = tid >> 6;           // 0..3 (4 waves)
  const int wm = (wid >> 1) * 64;     // wave tile m offset
  const int wn = (wid & 1) * 64;      // wave tile n offset
  const int m0 = blockIdx.y * 128;
  const int n0 = blockIdx.x * 128;
  const int quad = lane >> 4;         // 0..3
  const int l15 = lane & 15;

  f32x4 acc[4][4];
  #pragma unroll
  for (int i = 0; i < 4; ++i)
    #pragma unroll
    for (int j = 0; j < 4; ++j) {
      acc[i][j][0] = 0.f; acc[i][j][1] = 0.f; acc[i][j][2] = 0.f; acc[i][j][3] = 0.f;
    }

  // staging: 16 chunks of 1024B; wave w stages chunks 4w..4w+3 of each tile.
  // chunk c covers rows 8c..8c+7; lane covers row 8c+(lane>>3), 8 elems at swizzled col.
  const int srow = lane >> 3;                         // 0..7
  const int scol = ((lane & 7) << 3) ^ (srow << 3);   // pre-swizzled source col (elems)
  const short* aBase = A + (size_t)(m0 + wid * 32 + srow) * K + scol;
  const short* bBase = Bt + (size_t)(n0 + wid * 32 + srow) * K + scol;
  char* ldsA = (char*)&As[0][0];
  char* ldsB = (char*)&Bs[0][0];

  for (int kt = 0; kt < K; kt += 64) {
    __syncthreads();  // previous iteration's reads done before overwrite
    #pragma unroll
    for (int i = 0; i < 4; ++i) {
      __builtin_amdgcn_global_load_lds(
          (const __attribute__((address_space(1))) void*)(aBase + (size_t)(i * 8) * K + kt),
          (__attribute__((address_space(3))) void*)(ldsA + (wid * 4 + i) * 1024), 16, 0, 0);
      __builtin_amdgcn_global_load_lds(
          (const __attribute__((address_space(1))) void*)(bBase + (size_t)(i * 8) * K + kt),
          (__attribute__((address_space(3))) void*)(ldsB + (wid * 4 + i) * 1024), 16, 0, 0);
    }
    __syncthreads();  // drains vmcnt (global_load_lds) + lgkm

    #pragma unroll
    for (int ks = 0; ks < 2; ++ks) {
      bh8 af[4], bfr[4];
      // k-map per lane: k = ks*32 + quad*8 + j (self-consistent bijection for A and B
      // -> one ds_read_b128 per fragment; correct for any internal MFMA k-order).
      #pragma unroll
      for (int mi = 0; mi < 4; ++mi) {
        int row = wm + mi * 16 + l15;
        int col = ((ks << 5) + (quad << 3)) ^ ((row & 7) << 3);
        af[mi] = *(const bh8*)&As[row][col];
      }
      #pragma unroll
      for (int ni = 0; ni < 4; ++ni) {
        int row = wn + ni * 16 + l15;
        int col = ((ks << 5) + (quad << 3)) ^ ((row & 7) << 3);
        bfr[ni] = *(const bh8*)&Bs[row][col];
      }
      #pragma unroll
      for (int mi = 0; mi < 4; ++mi)
        #pragma unroll
        for (int ni = 0; ni < 4; ++ni)
          acc[mi][ni] = mfma_16x16x32_bf16(af[mi], bfr[ni], acc[mi][ni]);
    }
  }

  // Epilogue. D layout (m89-verified): n = l15, m = quad*4 + r.
  if (MODE == 0) {
    #pragma unroll
    for (int ni = 0; ni < 4; ++ni) {
      int n = n0 + wn + ni * 16 + l15;
      float bv = bias[n];
      #pragma unroll
      for (int mi = 0; mi < 4; ++mi) {
        int mrow = m0 + wm + mi * 16 + quad * 4;
        #pragma unroll
        for (int r = 0; r < 4; ++r) {
          float v = acc[mi][ni][r] + bv;
          C[(size_t)(mrow + r) * N + n] = f2b(silu_f(v));
        }
      }
    }
  } else {
    float part[4][4];
    #pragma unroll
    for (int mi = 0; mi < 4; ++mi)
      #pragma unroll
      for (int r = 0; r < 4; ++r) part[mi][r] = 0.f;
    #pragma unroll
    for (int ni = 0; ni < 4; ++ni) {
      int n = n0 + wn + ni * 16 + l15;
      float bv = bias[n];
      float wv = w3[n];
      #pragma unroll
      for (int mi = 0; mi < 4; ++mi)
        #pragma unroll
        for (int r = 0; r < 4; ++r)
          part[mi][r] += silu_f(acc[mi][ni][r] + bv) * wv;
    }
    #pragma unroll
    for (int mi = 0; mi < 4; ++mi)
      #pragma unroll
      for (int r = 0; r < 4; ++r) {
        float p = part[mi][r];
        p += __shfl_xor(p, 1);
        p += __shfl_xor(p, 2);
        p += __shfl_xor(p, 4);
        p += __shfl_xor(p, 8);
        if (l15 == 0) {
          int mrow = m0 + wm + mi * 16 + quad * 4 + r;
          atomicAdd(&eout[(size_t)mrow * NEXP + eidx], p);
        }
      }
  }
}

// ---------------- gating logits + softmax + final mix ----------------
// one wave per token row
__global__ __launch_bounds__(256) void final_kernel(
    const short* __restrict__ g2b, const float* __restrict__ Wg3,
    const float* __restrict__ bg3, const float* __restrict__ eout,
    const float* __restrict__ b3, float* __restrict__ out) {
  int row = blockIdx.x * 4 + (threadIdx.x >> 6);
  int lane = threadIdx.x & 63;
  float lp[16];
  #pragma unroll
  for (int j = 0; j < 16; ++j) lp[j] = 0.f;
  const short* grow = g2b + (size_t)row * HIDDEN;
  for (int t = 0; t < HIDDEN / 64; ++t) {
    int k = t * 64 + lane;
    float g = b2f(grow[k]);
    const float* wr = Wg3 + (size_t)k * NEXP;
    #pragma unroll
    for (int j = 0; j < 16; ++j) lp[j] = fmaf(g, wr[j], lp[j]);
  }
  #pragma unroll
  for (int j = 0; j < 16; ++j) {
    float v = lp[j];
    v += __shfl_xor(v, 1);  v += __shfl_xor(v, 2);  v += __shfl_xor(v, 4);
    v += __shfl_xor(v, 8);  v += __shfl_xor(v, 16); v += __shfl_xor(v, 32);
    lp[j] = v + bg3[j];
  }
  float mx = lp[0];
  #pragma unroll
  for (int j = 1; j < 16; ++j) mx = fmaxf(mx, lp[j]);
  float s = 0.f, accv = 0.f;
  #pragma unroll
  for (int j = 0; j < 16; ++j) {
    float p = __expf(lp[j] - mx);
    s += p;
    accv = fmaf(p, eout[(size_t)row * NEXP + j] + b3[j], accv);
  }
  if (lane == 0) out[row] = accv / s;
}

extern "C" void kernel_launch(void* const* d_in, const int* in_sizes, int n_in,
                              void* d_out, int out_size, void* d_ws, size_t ws_size,
                              hipStream_t stream) {
  const float* x   = (const float*)d_in[0];
  const float* W1  = (const float*)d_in[1];
  const float* b1  = (const float*)d_in[2];
  const float* W2  = (const float*)d_in[3];
  const float* b2  = (const float*)d_in[4];
  const float* W3  = (const float*)d_in[5];
  const float* b3  = (const float*)d_in[6];
  const float* Wg1 = (const float*)d_in[7];
  const float* bg1 = (const float*)d_in[8];
  const float* Wg2 = (const float*)d_in[9];
  const float* bg2 = (const float*)d_in[10];
  const float* Wg3 = (const float*)d_in[11];
  const float* bg3 = (const float*)d_in[12];
  float* out = (float*)d_out;

  // workspace layout (~92 MB)
  char* p = (char*)d_ws;
  short* xb   = (short*)p; p += (size_t)TOKENS * INF * 2;
  short* W1t  = (short*)p; p += (size_t)NEXP * HIDDEN * INF * 2;
  short* W2t  = (short*)p; p += (size_t)NEXP * HIDDEN * HIDDEN * 2;
  short* Wg1t = (short*)p; p += (size_t)HIDDEN * INF * 2;
  short* Wg2t = (short*)p; p += (size_t)HIDDEN * HIDDEN * 2;
  short* g2b  = (short*)p; p += (size_t)TOKENS * HIDDEN * 2;
  short* h1b  = (short*)p; p += (size_t)TOKENS * HIDDEN * 2;  // also reused as g1
  float* eout = (float*)p; p += (size_t)TOKENS * NEXP * 4;

  hipMemsetAsync(eout, 0, (size_t)TOKENS * NEXP * 4, stream);

  convert_kernel<<<1024, 256, 0, stream>>>(x, xb, TOKENS * INF);
  dim3 tb(32, 8);
  transpose_kernel<<<dim3(HIDDEN / 32, INF / 32, NEXP), tb, 0, stream>>>(W1, W1t, INF, HIDDEN);
  transpose_kernel<<<dim3(HIDDEN / 32, HIDDEN / 32, NEXP), tb, 0, stream>>>(W2, W2t, HIDDEN, HIDDEN);
  transpose_kernel<<<dim3(HIDDEN / 32, INF / 32, 1), tb, 0, stream>>>(Wg1, Wg1t, INF, HIDDEN);
  transpose_kernel<<<dim3(HIDDEN / 32, HIDDEN / 32, 1), tb, 0, stream>>>(Wg2, Wg2t, HIDDEN, HIDDEN);

  dim3 gg(HIDDEN / 128, TOKENS / 128);  // (8, 64)
  // gating: g1 (reuse h1b), then g2
  gemm_bf16<0><<<gg, 256, 0, stream>>>(xb, Wg1t, bg1, h1b, nullptr, nullptr, 0,
                                       TOKENS, HIDDEN, INF);
  gemm_bf16<0><<<gg, 256, 0, stream>>>(h1b, Wg2t, bg2, g2b, nullptr, nullptr, 0,
                                       TOKENS, HIDDEN, HIDDEN);
  // experts
  for (int e = 0; e < NEXP; ++e) {
    gemm_bf16<0><<<gg, 256, 0, stream>>>(xb, W1t + (size_t)e * HIDDEN * INF,
                                         b1 + (size_t)e * HIDDEN, h1b, nullptr, nullptr, 0,
                                         TOKENS, HIDDEN, INF);
    gemm_bf16<1><<<gg, 256, 0, stream>>>(h1b, W2t + (size_t)e * HIDDEN * HIDDEN,
                                         b2 + (size_t)e * HIDDEN, nullptr,
                                         W3 + (size_t)e * HIDDEN, eout, e,
                                         TOKENS, HIDDEN, HIDDEN);
  }

  final_kernel<<<TOKENS / 4, 256, 0, stream>>>(g2b, Wg3, bg3, eout, b3, out);
}

// Round 3
// 674.115 us; speedup vs baseline: 1.2074x; 1.2074x over previous
//
#include <hip/hip_runtime.h>

#define TOKENS 8192
#define INF 512
#define HIDDEN 1024
#define NEXP 16

typedef short bh4 __attribute__((ext_vector_type(4)));
typedef short bh8 __attribute__((ext_vector_type(8)));
typedef float f32x4 __attribute__((ext_vector_type(4)));

__device__ __forceinline__ short f2b(float f) {
  union { float f; unsigned u; } v; v.f = f;
  unsigned r = v.u + 0x7FFFu + ((v.u >> 16) & 1u);
  return (short)(r >> 16);
}
__device__ __forceinline__ float b2f(short h) {
  union { unsigned u; float f; } v; v.u = ((unsigned)(unsigned short)h) << 16;
  return v.f;
}
__device__ __forceinline__ float silu_f(float x) { return x / (1.f + __expf(-x)); }

// MFMA via inline asm; D tied to C with "+v".
__device__ __forceinline__ f32x4 mfma_16x16x32_bf16(bh8 a, bh8 b, f32x4 c) {
  asm("v_mfma_f32_16x16x32_bf16 %0, %1, %2, %0" : "+v"(c) : "v"(a), "v"(b));
  return c;
}

// ---------------- fp32 -> bf16 convert (vectorized) ----------------
__global__ __launch_bounds__(256) void convert_kernel(const float* __restrict__ in,
                                                      short* __restrict__ out, int n) {
  int nv = n >> 2;
  int stride = gridDim.x * blockDim.x;
  for (int i = blockIdx.x * blockDim.x + threadIdx.x; i < nv; i += stride) {
    float4 v = ((const float4*)in)[i];
    bh4 o;
    o[0] = f2b(v.x); o[1] = f2b(v.y); o[2] = f2b(v.z); o[3] = f2b(v.w);
    *(bh4*)(out + (size_t)i * 4) = o;
  }
}

// ---------------- batched transpose fp32 [R][C] -> bf16 [C][R] ----------------
__global__ __launch_bounds__(256) void transpose_kernel(const float* __restrict__ in,
                                                        short* __restrict__ out,
                                                        int R, int C) {
  __shared__ float tile[32][33];
  size_t base = (size_t)blockIdx.z * (size_t)R * (size_t)C;
  int c0 = blockIdx.x * 32, r0 = blockIdx.y * 32;
  int tx = threadIdx.x, ty = threadIdx.y;  // block (32,8)
  #pragma unroll
  for (int i = 0; i < 32; i += 8)
    tile[ty + i][tx] = in[base + (size_t)(r0 + ty + i) * C + (c0 + tx)];
  __syncthreads();
  #pragma unroll
  for (int i = 0; i < 32; i += 8)
    out[base + (size_t)(c0 + ty + i) * R + (r0 + tx)] = f2b(tile[tx][ty + i]);
}

// ---------------- 128x128-tile bf16 MFMA GEMM, z-batched over 17 jobs ----------------
// job = jobBase + blockIdx.z. Jobs 0..15 = experts, job 16 = gating.
// phase 1: C[z] = bf16(silu(acc + bias[n]))            (h1 slab / g1)
// phase 2: job<16 -> eout[m][job] += sum_n silu(acc+b2[n])*W3[job][n] (atomic)
//          job==16 -> g2b = bf16(silu(acc + bg2[n]))
__global__ __launch_bounds__(256) void gemm_moe(
    const short* __restrict__ Abase, size_t aStride,
    const short* __restrict__ BtE, const short* __restrict__ BtG, size_t bStride,
    const float* __restrict__ biasE, const float* __restrict__ biasG,
    short* __restrict__ Cbase, size_t cStride,
    const float* __restrict__ W3all, float* __restrict__ eout,
    int jobBase, int K, int phase) {
  __shared__ short As[128][64];
  __shared__ short Bs[128][64];
  const int z = blockIdx.z;
  const int job = jobBase + z;
  const short* A = Abase + (size_t)z * aStride;
  const short* Bt = (job < NEXP) ? BtE + (size_t)job * bStride : BtG;
  const float* bias = (job < NEXP) ? biasE + (size_t)job * HIDDEN : biasG;

  const int tid = threadIdx.x;
  const int lane = tid & 63;
  const int wid = tid >> 6;           // 0..3
  const int wm = (wid >> 1) * 64;
  const int wn = (wid & 1) * 64;
  const int m0 = blockIdx.y * 128;
  const int n0 = blockIdx.x * 128;
  const int quad = lane >> 4;
  const int l15 = lane & 15;

  f32x4 acc[4][4];
  #pragma unroll
  for (int i = 0; i < 4; ++i)
    #pragma unroll
    for (int j = 0; j < 4; ++j) {
      acc[i][j][0] = 0.f; acc[i][j][1] = 0.f; acc[i][j][2] = 0.f; acc[i][j][3] = 0.f;
    }

  const int srow = lane >> 3;                         // 0..7
  const int scol = ((lane & 7) << 3) ^ (srow << 3);   // pre-swizzled source col
  const short* aBase = A + (size_t)(m0 + wid * 32 + srow) * K + scol;
  const short* bBase = Bt + (size_t)(n0 + wid * 32 + srow) * K + scol;
  char* ldsA = (char*)&As[0][0];
  char* ldsB = (char*)&Bs[0][0];

  for (int kt = 0; kt < K; kt += 64) {
    __syncthreads();
    #pragma unroll
    for (int i = 0; i < 4; ++i) {
      __builtin_amdgcn_global_load_lds(
          (const __attribute__((address_space(1))) void*)(aBase + (size_t)(i * 8) * K + kt),
          (__attribute__((address_space(3))) void*)(ldsA + (wid * 4 + i) * 1024), 16, 0, 0);
      __builtin_amdgcn_global_load_lds(
          (const __attribute__((address_space(1))) void*)(bBase + (size_t)(i * 8) * K + kt),
          (__attribute__((address_space(3))) void*)(ldsB + (wid * 4 + i) * 1024), 16, 0, 0);
    }
    __syncthreads();

    #pragma unroll
    for (int ks = 0; ks < 2; ++ks) {
      bh8 af[4], bfr[4];
      #pragma unroll
      for (int mi = 0; mi < 4; ++mi) {
        int row = wm + mi * 16 + l15;
        int col = ((ks << 5) + (quad << 3)) ^ ((row & 7) << 3);
        af[mi] = *(const bh8*)&As[row][col];
      }
      #pragma unroll
      for (int ni = 0; ni < 4; ++ni) {
        int row = wn + ni * 16 + l15;
        int col = ((ks << 5) + (quad << 3)) ^ ((row & 7) << 3);
        bfr[ni] = *(const bh8*)&Bs[row][col];
      }
      #pragma unroll
      for (int mi = 0; mi < 4; ++mi)
        #pragma unroll
        for (int ni = 0; ni < 4; ++ni)
          acc[mi][ni] = mfma_16x16x32_bf16(af[mi], bfr[ni], acc[mi][ni]);
    }
  }

  // Epilogue. D layout: n = l15, m = quad*4 + r.
  if (phase == 1 || job == NEXP) {
    short* C = Cbase + (size_t)z * cStride;  // phase2 gating: cStride=0 -> g2b
    #pragma unroll
    for (int ni = 0; ni < 4; ++ni) {
      int n = n0 + wn + ni * 16 + l15;
      float bv = bias[n];
      #pragma unroll
      for (int mi = 0; mi < 4; ++mi) {
        int mrow = m0 + wm + mi * 16 + quad * 4;
        #pragma unroll
        for (int r = 0; r < 4; ++r) {
          float v = acc[mi][ni][r] + bv;
          C[(size_t)(mrow + r) * HIDDEN + n] = f2b(silu_f(v));
        }
      }
    }
  } else {
    const float* w3 = W3all + (size_t)job * HIDDEN;
    float part[4][4];
    #pragma unroll
    for (int mi = 0; mi < 4; ++mi)
      #pragma unroll
      for (int r = 0; r < 4; ++r) part[mi][r] = 0.f;
    #pragma unroll
    for (int ni = 0; ni < 4; ++ni) {
      int n = n0 + wn + ni * 16 + l15;
      float bv = bias[n];
      float wv = w3[n];
      #pragma unroll
      for (int mi = 0; mi < 4; ++mi)
        #pragma unroll
        for (int r = 0; r < 4; ++r)
          part[mi][r] += silu_f(acc[mi][ni][r] + bv) * wv;
    }
    #pragma unroll
    for (int mi = 0; mi < 4; ++mi)
      #pragma unroll
      for (int r = 0; r < 4; ++r) {
        float p = part[mi][r];
        p += __shfl_xor(p, 1);
        p += __shfl_xor(p, 2);
        p += __shfl_xor(p, 4);
        p += __shfl_xor(p, 8);
        if (l15 == 0) {
          int mrow = m0 + wm + mi * 16 + quad * 4 + r;
          atomicAdd(&eout[(size_t)mrow * NEXP + job], p);
        }
      }
  }
}

// ---------------- gating logits + softmax + final mix (round-1 verified logic) ----------------
// one wave per token row; Wg3 row loads vectorized as 4x float4 (same indices/math).
__global__ __launch_bounds__(256) void final_kernel(
    const short* __restrict__ g2b, const float* __restrict__ Wg3,
    const float* __restrict__ bg3, const float* __restrict__ eout,
    const float* __restrict__ b3, float* __restrict__ out) {
  int row = blockIdx.x * 4 + (threadIdx.x >> 6);
  int lane = threadIdx.x & 63;
  float lp[16];
  #pragma unroll
  for (int j = 0; j < 16; ++j) lp[j] = 0.f;
  const short* grow = g2b + (size_t)row * HIDDEN;
  for (int t = 0; t < HIDDEN / 64; ++t) {
    int k = t * 64 + lane;
    float g = b2f(grow[k]);
    const float4* wr4 = (const float4*)(Wg3 + (size_t)k * NEXP);
    float4 wa = wr4[0], wb = wr4[1], wc = wr4[2], wd = wr4[3];
    lp[0]  = fmaf(g, wa.x, lp[0]);  lp[1]  = fmaf(g, wa.y, lp[1]);
    lp[2]  = fmaf(g, wa.z, lp[2]);  lp[3]  = fmaf(g, wa.w, lp[3]);
    lp[4]  = fmaf(g, wb.x, lp[4]);  lp[5]  = fmaf(g, wb.y, lp[5]);
    lp[6]  = fmaf(g, wb.z, lp[6]);  lp[7]  = fmaf(g, wb.w, lp[7]);
    lp[8]  = fmaf(g, wc.x, lp[8]);  lp[9]  = fmaf(g, wc.y, lp[9]);
    lp[10] = fmaf(g, wc.z, lp[10]); lp[11] = fmaf(g, wc.w, lp[11]);
    lp[12] = fmaf(g, wd.x, lp[12]); lp[13] = fmaf(g, wd.y, lp[13]);
    lp[14] = fmaf(g, wd.z, lp[14]); lp[15] = fmaf(g, wd.w, lp[15]);
  }
  #pragma unroll
  for (int j = 0; j < 16; ++j) {
    float v = lp[j];
    v += __shfl_xor(v, 1);  v += __shfl_xor(v, 2);  v += __shfl_xor(v, 4);
    v += __shfl_xor(v, 8);  v += __shfl_xor(v, 16); v += __shfl_xor(v, 32);
    lp[j] = v + bg3[j];
  }
  float mx = lp[0];
  #pragma unroll
  for (int j = 1; j < 16; ++j) mx = fmaxf(mx, lp[j]);
  float s = 0.f, accv = 0.f;
  #pragma unroll
  for (int j = 0; j < 16; ++j) {
    float p = __expf(lp[j] - mx);
    s += p;
    accv = fmaf(p, eout[(size_t)row * NEXP + j] + b3[j], accv);
  }
  if (lane == 0) out[row] = accv / s;
}

extern "C" void kernel_launch(void* const* d_in, const int* in_sizes, int n_in,
                              void* d_out, int out_size, void* d_ws, size_t ws_size,
                              hipStream_t stream) {
  const float* x   = (const float*)d_in[0];
  const float* W1  = (const float*)d_in[1];
  const float* b1  = (const float*)d_in[2];
  const float* W2  = (const float*)d_in[3];
  const float* b2  = (const float*)d_in[4];
  const float* W3  = (const float*)d_in[5];
  const float* b3  = (const float*)d_in[6];
  const float* Wg1 = (const float*)d_in[7];
  const float* bg1 = (const float*)d_in[8];
  const float* Wg2 = (const float*)d_in[9];
  const float* bg2 = (const float*)d_in[10];
  const float* Wg3 = (const float*)d_in[11];
  const float* bg3 = (const float*)d_in[12];
  float* out = (float*)d_out;

  // workspace layout: fixed region (~75.5 MB) + h1 slab (as many 16MB slots as fit)
  char* p = (char*)d_ws;
  short* xb   = (short*)p; p += (size_t)TOKENS * INF * 2;
  short* W1t  = (short*)p; p += (size_t)NEXP * HIDDEN * INF * 2;
  short* W2t  = (short*)p; p += (size_t)NEXP * HIDDEN * HIDDEN * 2;
  short* Wg1t = (short*)p; p += (size_t)HIDDEN * INF * 2;
  short* Wg2t = (short*)p; p += (size_t)HIDDEN * HIDDEN * 2;
  short* g2b  = (short*)p; p += (size_t)TOKENS * HIDDEN * 2;
  float* eout = (float*)p; p += (size_t)TOKENS * NEXP * 4;
  size_t fixedBytes = (size_t)(p - (char*)d_ws);
  short* h1slab = (short*)p;
  const size_t SLOT_ELEMS = (size_t)TOKENS * HIDDEN;       // per-job h1 elements
  const size_t SLOT_BYTES = SLOT_ELEMS * 2;                // 16 MB
  size_t avail = ws_size > fixedBytes ? ws_size - fixedBytes : 0;
  int slots = (int)(avail / SLOT_BYTES);
  if (slots > NEXP + 1) slots = NEXP + 1;
  if (slots < 1) slots = 1;  // round-1 layout used ~91.5MB successfully

  hipMemsetAsync(eout, 0, (size_t)TOKENS * NEXP * 4, stream);

  convert_kernel<<<1024, 256, 0, stream>>>(x, xb, TOKENS * INF);
  dim3 tb(32, 8);
  transpose_kernel<<<dim3(HIDDEN / 32, INF / 32, NEXP), tb, 0, stream>>>(W1, W1t, INF, HIDDEN);
  transpose_kernel<<<dim3(HIDDEN / 32, HIDDEN / 32, NEXP), tb, 0, stream>>>(W2, W2t, HIDDEN, HIDDEN);
  transpose_kernel<<<dim3(HIDDEN / 32, INF / 32, 1), tb, 0, stream>>>(Wg1, Wg1t, INF, HIDDEN);
  transpose_kernel<<<dim3(HIDDEN / 32, HIDDEN / 32, 1), tb, 0, stream>>>(Wg2, Wg2t, HIDDEN, HIDDEN);

  // 17 jobs: experts 0..15 + gating (job 16), processed in groups of `slots`
  for (int base = 0; base < NEXP + 1; base += slots) {
    int cnt = NEXP + 1 - base;
    if (cnt > slots) cnt = slots;
    dim3 gg(HIDDEN / 128, TOKENS / 128, cnt);  // (8, 64, cnt)
    // layer 1: A = xb (shared), C = h1 slab slot z
    gemm_moe<<<gg, 256, 0, stream>>>(xb, 0, W1t, Wg1t, (size_t)INF * HIDDEN,
                                     b1, bg1, h1slab, SLOT_ELEMS,
                                     nullptr, nullptr, base, INF, 1);
    // layer 2: A = h1 slot z; experts reduce into eout, gating writes g2b
    gemm_moe<<<gg, 256, 0, stream>>>(h1slab, SLOT_ELEMS, W2t, Wg2t, (size_t)HIDDEN * HIDDEN,
                                     b2, bg2, g2b, 0,
                                     W3, eout, base, HIDDEN, 2);
  }

  final_kernel<<<TOKENS / 4, 256, 0, stream>>>(g2b, Wg3, bg3, eout, b3, out);
}